// Round 6
// baseline (5430.945 us; speedup 1.0000x reference)
//
#include <hip/hip_runtime.h>
#include <math.h>

#define BB   4
#define NPTS 4096
#define NNODE (BB*NPTS)
#define CC   64
#define HHH  4
#define KK   16
#define D1   67
#define SD1  68     // padded row stride for xcat
#define SD2  64
#define NSTR 16     // candidate streams (= waves) per knn block
#define MST  (NSTR*KK + 2)   // per-node merge stride (258): 16*16 entries + 2 pad

// ---------------------------------------------------------------- prep:
// build xcat fp32 [NNODE][68] = [features(64) | coords(3) | 0pad] and ||x||^2
__global__ __launch_bounds__(256) void k_prep(const float* __restrict__ pf,
                                              const float* __restrict__ pt,
                                              float* __restrict__ xcat,
                                              float* __restrict__ x2)
{
    int node = blockIdx.x*256 + threadIdx.x;
    int b = node >> 12, n = node & (NPTS-1);
    const float* pfb = pf + (size_t)b*CC*NPTS + n;
    const float* ptb = pt + (size_t)b*3*NPTS + n;
    float* row = xcat + (size_t)node*SD1;
    float acc = 0.f;
    #pragma unroll 8
    for (int c=0;c<CC;c++){ float v = pfb[(size_t)c*NPTS]; row[c]=v; acc = fmaf(v,v,acc); }
    #pragma unroll
    for (int c=0;c<3;c++){ float v = ptb[(size_t)c*NPTS]; row[CC+c]=v; acc = fmaf(v,v,acc); }
    row[SD1-1]=0.f;
    x2[node]=acc;
}

// ---------------------------------------------------------------- fused knn
// block = 1024 threads = 16 waves, owns 64 consecutive nodes (node = base + lane).
// wave w scans candidates c with (c mod 16)==w in ascending order -> sorted
// register top-16 per lane; then thread l (<64) serially 16-way-merges node l's
// sorted lists (lexicographic (d, idx) == jax.lax.top_k lowest-index tie-break).
__device__ __forceinline__ void topk_insert(float (&dk)[KK], int (&ik)[KK], float d, int g){
    if (d < dk[KK-1]){            // strict < : first-seen (lowest index) wins ties
        dk[KK-1]=d; ik[KK-1]=g;
        #pragma unroll
        for (int j=KK-1;j>0;j--){
            bool sw = dk[j] < dk[j-1];
            float a=dk[j-1], b=dk[j]; int ia=ik[j-1], ib=ik[j];
            dk[j-1]=sw?b:a;  dk[j]=sw?a:b;
            ik[j-1]=sw?ib:ia; ik[j]=sw?ia:ib;
        }
    }
}

template<int SD>
__global__ __launch_bounds__(1024, 4) void k_knn(const float* __restrict__ X,
    const float* __restrict__ x2, int* __restrict__ nbr)
{
    // LDS: merge arrays dominate; the scan tile + t2 alias the head of mdf
    // (tile/t2 dead before mdf is written; phases separated by __syncthreads).
    __shared__ __align__(16) float mdf[64*MST];   // 66048 B  [node][stream*16+entry]
    __shared__ __align__(16) int   mii[64*MST];   // 66048 B
    float* tile = mdf;              // 64*SD floats (<= 17408 B)
    float* t2   = mdf + 64*SD;      // 64 floats

    const int tid = threadIdx.x;
    const int w = tid>>6, l = tid&63;   // stream = wave id, node-lane = l
    const int b = blockIdx.y;
    const int nodeBase = b*NPTS + blockIdx.x*64;
    const int node = nodeBase + l;

    float4 xt[SD/4];
    const float4* xr = (const float4*)(X + (size_t)node*SD);
    #pragma unroll
    for (int i=0;i<SD/4;i++) xt[i]=xr[i];
    const float x2t = x2[node];

    float dk[KK]; int ik[KK];
    #pragma unroll
    for (int i=0;i<KK;i++){ dk[i]=INFINITY; ik[i]=0x7fffffff; }

    const int base = b*NPTS;
    for (int t=0; t<NPTS/64; t++){
        int cb = base + t*64;
        __syncthreads();   // previous tile fully consumed
        { // stage 64 candidate rows (contiguous: row stride == SD)
            const float4* src = (const float4*)(X + (size_t)cb*SD);
            float4* dst = (float4*)tile;
            for (int i=tid; i<16*SD; i+=1024) dst[i]=src[i];
            if (tid < 64) t2[tid]=x2[cb+tid];
        }
        __syncthreads();
        // wave w handles local candidates {w, w+16, w+32, w+48}, ascending,
        // two per iteration (c0, c0+16) for 4 independent FMA chains.
        #pragma unroll 1
        for (int q=0;q<2;q++){
            int c0 = w + 32*q, c1 = c0 + 16;
            float a0=0.f,b0=0.f,a1=0.f,b1=0.f;
            const float* r0 = tile + c0*SD;
            const float* r1 = tile + c1*SD;
            #pragma unroll
            for (int i=0;i<SD/4;i++){
                float4 v = xt[i];
                const float* p0 = r0 + 4*i;
                const float* p1 = r1 + 4*i;
                if ((i&1)==0){
                    a0 = fmaf(v.w,p0[3], fmaf(v.z,p0[2], fmaf(v.y,p0[1], fmaf(v.x,p0[0], a0))));
                    a1 = fmaf(v.w,p1[3], fmaf(v.z,p1[2], fmaf(v.y,p1[1], fmaf(v.x,p1[0], a1))));
                } else {
                    b0 = fmaf(v.w,p0[3], fmaf(v.z,p0[2], fmaf(v.y,p0[1], fmaf(v.x,p0[0], b0))));
                    b1 = fmaf(v.w,p1[3], fmaf(v.z,p1[2], fmaf(v.y,p1[1], fmaf(v.x,p1[0], b1))));
                }
            }
            float dot0=a0+b0, dot1=a1+b1;
            int g0 = cb + c0, g1 = cb + c1;
            // reference order: (x2_t - 2*dot) + x2_c   (2*dot exact, fmaf == np rounding)
            float dd0 = fmaf(-2.f, dot0, x2t) + t2[c0];
            float dd1 = fmaf(-2.f, dot1, x2t) + t2[c1];
            if (g0==node) dd0 = INFINITY;   // exclude self
            if (g1==node) dd1 = INFINITY;
            topk_insert(dk, ik, dd0, g0);
            topk_insert(dk, ik, dd1, g1);
        }
    }
    // ---- publish sorted per-stream lists (tile/t2 dead from here)
    __syncthreads();
    #pragma unroll
    for (int i=0;i<KK;i++){ mdf[l*MST + w*KK + i]=dk[i]; mii[l*MST + w*KK + i]=ik[i]; }
    __syncthreads();
    // ---- serial 16-way merge with register-cached heads: thread l (<64) owns node l
    if (tid < 64){
        const float* mdl = mdf + tid*MST;
        const int*   mil = mii + tid*MST;
        float hd[NSTR]; int hi[NSTR]; int pp[NSTR];
        #pragma unroll
        for (int s=0;s<NSTR;s++){ pp[s]=0; hd[s]=mdl[s*KK]; hi[s]=mil[s*KK]; }
        int obase = (nodeBase + tid)*KK;
        #pragma unroll 1
        for (int r=0;r<KK;r++){
            float bd=hd[0]; int bi=hi[0]; int bw=0;
            #pragma unroll
            for (int s=1;s<NSTR;s++){
                if (hd[s]<bd || (hd[s]==bd && hi[s]<bi)){ bd=hd[s]; bi=hi[s]; bw=s; }
            }
            nbr[obase + r] = bi;
            #pragma unroll
            for (int s=0;s<NSTR;s++){
                if (bw==s){
                    int np = ++pp[s];
                    bool ok = np < KK;
                    // np==KK reads the pad; value discarded by select
                    float nv = mdl[s*KK + np];
                    int   ni = mil[s*KK + np];
                    hd[s] = ok ? nv : INFINITY;
                    hi[s] = ok ? ni : 0x7fffffff;
                }
            }
        }
    }
}

// ---------------------------------------------------------------- h = X@W, asrc, adst
template<int SD, int D>
__global__ __launch_bounds__(256) void k_gemm_h(const float* __restrict__ X,
    const float* __restrict__ W, const float* __restrict__ a_s,
    const float* __restrict__ a_d,
    float* __restrict__ h, float* __restrict__ asrc, float* __restrict__ adst)
{
    __shared__ float Wl[D*CC];
    __shared__ float asl[CC], adl[CC];
    const int tid = threadIdx.x;
    for (int i=tid;i<D*CC;i+=256) Wl[i]=W[i];
    if (tid<CC){ asl[tid]=a_s[tid]; adl[tid]=a_d[tid]; }
    __syncthreads();

    const int node = blockIdx.x*256 + tid;
    float xr[SD];
    const float4* xp = (const float4*)(X + (size_t)node*SD);
    #pragma unroll
    for (int i=0;i<SD/4;i++){ float4 v=xp[i]; xr[4*i]=v.x; xr[4*i+1]=v.y; xr[4*i+2]=v.z; xr[4*i+3]=v.w; }

    float sacc[HHH]={0,0,0,0}, dacc[HHH]={0,0,0,0};
    float* hrow = h + (size_t)node*CC;
    #pragma unroll 1
    for (int c4=0;c4<CC/4;c4++){
        float acc[4]={0,0,0,0};
        #pragma unroll
        for (int d=0;d<D;d++){
            const float* wp = Wl + d*CC + c4*4;
            float xv = xr[d];
            acc[0]=fmaf(xv,wp[0],acc[0]); acc[1]=fmaf(xv,wp[1],acc[1]);
            acc[2]=fmaf(xv,wp[2],acc[2]); acc[3]=fmaf(xv,wp[3],acc[3]);
        }
        int hh = c4 >> 2;
        #pragma unroll
        for (int j=0;j<4;j++){
            int c = c4*4+j;
            sacc[hh] = fmaf(acc[j], asl[c], sacc[hh]);
            dacc[hh] = fmaf(acc[j], adl[c], dacc[hh]);
        }
        ((float4*)hrow)[c4] = make_float4(acc[0],acc[1],acc[2],acc[3]);
    }
    #pragma unroll
    for (int q=0;q<HHH;q++){ asrc[(size_t)node*HHH+q]=sacc[q]; adst[(size_t)node*HHH+q]=dacc[q]; }
}

// ---------------------------------------------------------------- GAT gather+softmax+PV
__global__ __launch_bounds__(256) void k_gat(const float* __restrict__ h,
    const float* __restrict__ asrc, const float* __restrict__ adst,
    const int* __restrict__ nbr, const float* __restrict__ bias,
    float* __restrict__ f, float* __restrict__ x2out)
{
    int wid = threadIdx.x>>6, lane = threadIdx.x&63;
    int node = blockIdx.x*4 + wid;
    int hh = lane>>4;
    float ad = adst[(size_t)node*HHH+hh];
    int js[KK]; float e[KK];
    #pragma unroll
    for (int k=0;k<KK;k++){
        int j = nbr[node*KK+k] & (NNODE-1);    // clamp: garbage -> numeric error, never a fault
        js[k]=j;
        float ev = asrc[(size_t)j*HHH+hh] + ad;
        e[k] = ev>0.f ? ev : 0.2f*ev;          // leaky_relu 0.2
    }
    float m = e[0];
    #pragma unroll
    for (int k=1;k<KK;k++) m = fmaxf(m,e[k]);
    float s=0.f;
    #pragma unroll
    for (int k=0;k<KK;k++){ e[k]=__expf(e[k]-m); s+=e[k]; }
    float inv = 1.f/s;
    float acc=0.f;
    #pragma unroll
    for (int k=0;k<KK;k++)
        acc = fmaf(e[k]*inv, h[(size_t)js[k]*CC + lane], acc);
    float val = acc + bias[lane];
    val = val>0.f ? val : expm1f(val);          // elu
    f[(size_t)node*CC+lane]=val;
    float sq = val*val;
    #pragma unroll
    for (int s2=32;s2>0;s2>>=1) sq += __shfl_xor(sq, s2);
    if (lane==0) x2out[node]=sq;
}

// ---------------------------------------------------------------- final MLP + transpose-out
__global__ __launch_bounds__(256) void k_final(const float* __restrict__ f1,
    const float* __restrict__ f2, const float* __restrict__ Wm,
    const float* __restrict__ bm, float* __restrict__ out)
{
    __shared__ float Wl[2*CC*CC];   // 128x64 fp32 = 32 KB
    const int tid=threadIdx.x;
    for (int i=tid;i<2*CC*CC;i+=256) Wl[i]=Wm[i];
    __syncthreads();
    int node = blockIdx.x*256 + tid;
    int b = node>>12, n = node&(NPTS-1);
    float xr[2*CC];
    const float4* p1=(const float4*)(f1 + (size_t)node*CC);
    const float4* p2=(const float4*)(f2 + (size_t)node*CC);
    #pragma unroll
    for (int i=0;i<CC/4;i++){ float4 v=p1[i]; xr[4*i]=v.x; xr[4*i+1]=v.y; xr[4*i+2]=v.z; xr[4*i+3]=v.w; }
    #pragma unroll
    for (int i=0;i<CC/4;i++){ float4 v=p2[i]; xr[CC+4*i]=v.x; xr[CC+4*i+1]=v.y; xr[CC+4*i+2]=v.z; xr[CC+4*i+3]=v.w; }
    #pragma unroll 1
    for (int c4=0;c4<CC/4;c4++){
        float acc[4]={0,0,0,0};
        #pragma unroll
        for (int d=0;d<2*CC;d++){
            const float* wp = Wl + d*CC + c4*4;
            float xv=xr[d];
            acc[0]=fmaf(xv,wp[0],acc[0]); acc[1]=fmaf(xv,wp[1],acc[1]);
            acc[2]=fmaf(xv,wp[2],acc[2]); acc[3]=fmaf(xv,wp[3],acc[3]);
        }
        #pragma unroll
        for (int j=0;j<4;j++){
            int c=c4*4+j;
            float v = acc[j] + bm[c];
            v = v>0.f ? v : expm1f(v);
            out[(size_t)b*CC*NPTS + (size_t)c*NPTS + n] = v;
        }
    }
}

// ---------------------------------------------------------------- ws-too-small fallback
__global__ void k_zero(float* out, int n){
    int i = blockIdx.x*256 + threadIdx.x;
    if (i<n) out[i] = 0.f;
}

// ---------------------------------------------------------------- launcher
extern "C" void kernel_launch(void* const* d_in, const int* in_sizes, int n_in,
                              void* d_out, int out_size, void* d_ws, size_t ws_size,
                              hipStream_t stream) {
    const float* pf  = (const float*)d_in[0];
    const float* pt  = (const float*)d_in[1];
    const float* W1  = (const float*)d_in[2];
    const float* a1s = (const float*)d_in[3];
    const float* a1d = (const float*)d_in[4];
    const float* b1  = (const float*)d_in[5];
    const float* W2  = (const float*)d_in[6];
    const float* a2s = (const float*)d_in[7];
    const float* a2d = (const float*)d_in[8];
    const float* b2  = (const float*)d_in[9];
    const float* Wm  = (const float*)d_in[10];
    const float* bm  = (const float*)d_in[11];
    float* out = (float*)d_out;

    // ---- workspace layout (floats), ~14.5 MB; f2 aliases xcat (dead after gemm1)
    float* ws = (float*)d_ws;
    float* xcat  = ws;                             // 16384*68
    float* f2    = xcat;                           // alias
    float* h     = xcat + (size_t)NNODE*SD1;       // 16384*64
    float* f1    = h    + (size_t)NNODE*CC;        // 16384*64
    int*   nbr   = (int*)(f1 + (size_t)NNODE*CC);  // 16384*16
    float* x2    = (float*)(nbr + (size_t)NNODE*KK); // 16384
    float* asrc  = x2   + NNODE;                   // 16384*4
    float* adst  = asrc + (size_t)NNODE*HHH;       // 16384*4
    size_t need  = (size_t)((adst + (size_t)NNODE*HHH) - ws) * sizeof(float);
    if (ws_size < need) {   // diagnostic fallback: clean numeric fail, not a crash
        k_zero<<<(out_size+255)/256, 256, 0, stream>>>(out, out_size);
        return;
    }

    dim3 knnGrid(NPTS/64, BB);   // 256 blocks x 1024 threads -> 16 waves/CU (4/SIMD)

    k_prep<<<NNODE/256, 256, 0, stream>>>(pf, pt, xcat, x2);
    k_knn<SD1><<<knnGrid, 1024, 0, stream>>>(xcat, x2, nbr);
    k_gemm_h<SD1, D1><<<NNODE/256, 256, 0, stream>>>(xcat, W1, a1s, a1d, h, asrc, adst);
    k_gat<<<NNODE/4, 256, 0, stream>>>(h, asrc, adst, nbr, b1, f1, x2);
    k_knn<SD2><<<knnGrid, 1024, 0, stream>>>(f1, x2, nbr);
    k_gemm_h<SD2, CC><<<NNODE/256, 256, 0, stream>>>(f1, W2, a2s, a2d, h, asrc, adst);
    k_gat<<<NNODE/4, 256, 0, stream>>>(h, asrc, adst, nbr, b2, f2, x2);
    k_final<<<NNODE/256, 256, 0, stream>>>(f1, f2, Wm, bm, out);
}

// Round 7
// 1256.538 us; speedup vs baseline: 4.3221x; 4.3221x over previous
//
#include <hip/hip_runtime.h>
#include <math.h>

#define BB   4
#define NPTS 4096
#define NNODE (BB*NPTS)
#define CC   64
#define HHH  4
#define KK   16
#define D1   67
#define SD1  68     // padded row stride for xcat
#define SD2  64
#define NSTR 8      // candidate streams (= waves) per knn block
#define NSEG 2      // candidate segments (blockIdx.z)
#define SEGC (NPTS/NSEG)     // 2048 candidates per segment
#define MST  (NSTR*KK + 2)   // per-node merge stride (130 floats)

// ---------------------------------------------------------------- prep:
// build xcat fp32 [NNODE][68] = [features(64) | coords(3) | 0pad] and ||x||^2
__global__ __launch_bounds__(256) void k_prep(const float* __restrict__ pf,
                                              const float* __restrict__ pt,
                                              float* __restrict__ xcat,
                                              float* __restrict__ x2)
{
    int node = blockIdx.x*256 + threadIdx.x;
    int b = node >> 12, n = node & (NPTS-1);
    const float* pfb = pf + (size_t)b*CC*NPTS + n;
    const float* ptb = pt + (size_t)b*3*NPTS + n;
    float* row = xcat + (size_t)node*SD1;
    float acc = 0.f;
    #pragma unroll 8
    for (int c=0;c<CC;c++){ float v = pfb[(size_t)c*NPTS]; row[c]=v; acc = fmaf(v,v,acc); }
    #pragma unroll
    for (int c=0;c<3;c++){ float v = ptb[(size_t)c*NPTS]; row[CC+c]=v; acc = fmaf(v,v,acc); }
    row[SD1-1]=0.f;
    x2[node]=acc;
}

// ---------------------------------------------------------------- fused knn (per segment)
// block = 512 threads = 8 waves, owns 64 consecutive nodes (node = base + lane),
// scans candidate segment [segbase, segbase+2048). wave w scans candidates
// c ≡ w (mod 8) ascending -> sorted register top-16 per lane; block-internal
// 8-way merge -> sorted per-node 16-list for this segment (partd/parti).
// Lexicographic (d, idx) == jax.lax.top_k lowest-index tie-break throughout.
__device__ __forceinline__ void topk_insert(float (&dk)[KK], int (&ik)[KK], float d, int g){
    if (d < dk[KK-1]){            // strict < : first-seen (lowest index) wins ties
        dk[KK-1]=d; ik[KK-1]=g;
        #pragma unroll
        for (int j=KK-1;j>0;j--){
            bool sw = dk[j] < dk[j-1];
            float a=dk[j-1], b=dk[j]; int ia=ik[j-1], ib=ik[j];
            dk[j-1]=sw?b:a;  dk[j]=sw?a:b;
            ik[j-1]=sw?ib:ia; ik[j]=sw?ia:ib;
        }
    }
}

template<int SD>
__global__ __launch_bounds__(512) void k_knn_seg(const float* __restrict__ X,
    const float* __restrict__ x2, float* __restrict__ partd, int* __restrict__ parti)
{
    // LDS: merge arrays dominate; scan tile + t2 alias the head of mdf
    // (tile/t2 dead before mdf is written; phases separated by __syncthreads).
    __shared__ __align__(16) float mdf[64*MST];   // 33280 B [node][stream*16+entry]
    __shared__ __align__(16) int   mii[64*MST];   // 33280 B
    float* tile = mdf;              // 64*SD floats (<= 17408 B, fits in mdf)
    float* t2   = mdf + 64*SD;      // 64 floats

    const int tid = threadIdx.x;
    const int w = tid>>6, l = tid&63;   // stream = wave id, node-lane = l
    const int b = blockIdx.y, seg = blockIdx.z;
    const int nodeBase = b*NPTS + blockIdx.x*64;
    const int node = nodeBase + l;

    float4 xt[SD/4];
    const float4* xr = (const float4*)(X + (size_t)node*SD);
    #pragma unroll
    for (int i=0;i<SD/4;i++) xt[i]=xr[i];
    const float x2t = x2[node];

    float dk[KK]; int ik[KK];
    #pragma unroll
    for (int i=0;i<KK;i++){ dk[i]=INFINITY; ik[i]=0x7fffffff; }

    const int segbase = b*NPTS + seg*SEGC;
    for (int t=0; t<SEGC/64; t++){
        int cb = segbase + t*64;
        __syncthreads();   // previous tile fully consumed
        { // stage 64 candidate rows (contiguous: row stride == SD)
            const float4* src = (const float4*)(X + (size_t)cb*SD);
            float4* dst = (float4*)tile;
            for (int i=tid; i<16*SD; i+=512) dst[i]=src[i];
            if (tid < 64) t2[tid]=x2[cb+tid];
        }
        __syncthreads();
        // wave w handles local candidates {w, w+8, ..., w+56}, ascending,
        // two per iteration (c0, c0+8) for 4 independent FMA chains.
        #pragma unroll 1
        for (int q=0;q<4;q++){
            int c0 = w + 16*q, c1 = c0 + 8;
            float a0=0.f,b0=0.f,a1=0.f,b1=0.f;
            const float* r0 = tile + c0*SD;
            const float* r1 = tile + c1*SD;
            #pragma unroll
            for (int i=0;i<SD/4;i++){
                float4 v = xt[i];
                const float* p0 = r0 + 4*i;
                const float* p1 = r1 + 4*i;
                if ((i&1)==0){
                    a0 = fmaf(v.w,p0[3], fmaf(v.z,p0[2], fmaf(v.y,p0[1], fmaf(v.x,p0[0], a0))));
                    a1 = fmaf(v.w,p1[3], fmaf(v.z,p1[2], fmaf(v.y,p1[1], fmaf(v.x,p1[0], a1))));
                } else {
                    b0 = fmaf(v.w,p0[3], fmaf(v.z,p0[2], fmaf(v.y,p0[1], fmaf(v.x,p0[0], b0))));
                    b1 = fmaf(v.w,p1[3], fmaf(v.z,p1[2], fmaf(v.y,p1[1], fmaf(v.x,p1[0], b1))));
                }
            }
            float dot0=a0+b0, dot1=a1+b1;
            int g0 = cb + c0, g1 = cb + c1;
            // reference order: (x2_t - 2*dot) + x2_c   (2*dot exact, fmaf == np rounding)
            float dd0 = fmaf(-2.f, dot0, x2t) + t2[c0];
            float dd1 = fmaf(-2.f, dot1, x2t) + t2[c1];
            if (g0==node) dd0 = INFINITY;   // exclude self
            if (g1==node) dd1 = INFINITY;
            topk_insert(dk, ik, dd0, g0);
            topk_insert(dk, ik, dd1, g1);
        }
    }
    // ---- publish sorted per-stream lists (tile/t2 dead from here)
    __syncthreads();
    #pragma unroll
    for (int i=0;i<KK;i++){ mdf[l*MST + w*KK + i]=dk[i]; mii[l*MST + w*KK + i]=ik[i]; }
    __syncthreads();
    // ---- serial 8-way merge with register-cached heads: thread l (<64) owns node l;
    // writes this segment's sorted 16-list (d and idx) to global partials.
    if (tid < 64){
        const float* mdl = mdf + tid*MST;
        const int*   mil = mii + tid*MST;
        float hd[NSTR]; int hi[NSTR]; int pp[NSTR];
        #pragma unroll
        for (int s=0;s<NSTR;s++){ pp[s]=0; hd[s]=mdl[s*KK]; hi[s]=mil[s*KK]; }
        size_t obase = ((size_t)(nodeBase + tid)*NSEG + seg)*KK;
        #pragma unroll 1
        for (int r=0;r<KK;r++){
            float bd=hd[0]; int bi=hi[0]; int bw=0;
            #pragma unroll
            for (int s=1;s<NSTR;s++){
                if (hd[s]<bd || (hd[s]==bd && hi[s]<bi)){ bd=hd[s]; bi=hi[s]; bw=s; }
            }
            partd[obase + r] = bd;
            parti[obase + r] = bi;
            #pragma unroll
            for (int s=0;s<NSTR;s++){
                if (bw==s){
                    int np = ++pp[s];
                    bool ok = np < KK;
                    float nv = mdl[s*KK + np];  // np==KK reads pad; discarded by select
                    int   ni = mil[s*KK + np];
                    hd[s] = ok ? nv : INFINITY;
                    hi[s] = ok ? ni : 0x7fffffff;
                }
            }
        }
    }
}

// ---------------------------------------------------------------- merge 2 sorted 16-lists -> nbr
__global__ __launch_bounds__(256) void k_merge2(const float* __restrict__ partd,
    const int* __restrict__ parti, int* __restrict__ nbr)
{
    int node = blockIdx.x*256 + threadIdx.x;
    const float* d0 = partd + (size_t)node*NSEG*KK;
    const int*   i0 = parti + (size_t)node*NSEG*KK;
    int pa=0, pb=KK;
    int obase = node*KK;
    #pragma unroll 1
    for (int r=0;r<KK;r++){
        float da = d0[pa]; int ia = i0[pa];
        float db = d0[pb]; int ib = i0[pb];
        bool takeA = (da<db) || (da==db && ia<ib);   // lex (d, idx)
        nbr[obase+r] = takeA ? ia : ib;
        if (takeA) pa++; else pb++;
    }
}

// ---------------------------------------------------------------- h = X@W, asrc, adst
template<int SD, int D>
__global__ __launch_bounds__(256) void k_gemm_h(const float* __restrict__ X,
    const float* __restrict__ W, const float* __restrict__ a_s,
    const float* __restrict__ a_d,
    float* __restrict__ h, float* __restrict__ asrc, float* __restrict__ adst)
{
    __shared__ float Wl[D*CC];
    __shared__ float asl[CC], adl[CC];
    const int tid = threadIdx.x;
    for (int i=tid;i<D*CC;i+=256) Wl[i]=W[i];
    if (tid<CC){ asl[tid]=a_s[tid]; adl[tid]=a_d[tid]; }
    __syncthreads();

    const int node = blockIdx.x*256 + tid;
    float xr[SD];
    const float4* xp = (const float4*)(X + (size_t)node*SD);
    #pragma unroll
    for (int i=0;i<SD/4;i++){ float4 v=xp[i]; xr[4*i]=v.x; xr[4*i+1]=v.y; xr[4*i+2]=v.z; xr[4*i+3]=v.w; }

    float sacc[HHH]={0,0,0,0}, dacc[HHH]={0,0,0,0};
    float* hrow = h + (size_t)node*CC;
    #pragma unroll 1
    for (int c4=0;c4<CC/4;c4++){
        float acc[4]={0,0,0,0};
        #pragma unroll
        for (int d=0;d<D;d++){
            const float* wp = Wl + d*CC + c4*4;
            float xv = xr[d];
            acc[0]=fmaf(xv,wp[0],acc[0]); acc[1]=fmaf(xv,wp[1],acc[1]);
            acc[2]=fmaf(xv,wp[2],acc[2]); acc[3]=fmaf(xv,wp[3],acc[3]);
        }
        int hh = c4 >> 2;
        #pragma unroll
        for (int j=0;j<4;j++){
            int c = c4*4+j;
            sacc[hh] = fmaf(acc[j], asl[c], sacc[hh]);
            dacc[hh] = fmaf(acc[j], adl[c], dacc[hh]);
        }
        ((float4*)hrow)[c4] = make_float4(acc[0],acc[1],acc[2],acc[3]);
    }
    #pragma unroll
    for (int q=0;q<HHH;q++){ asrc[(size_t)node*HHH+q]=sacc[q]; adst[(size_t)node*HHH+q]=dacc[q]; }
}

// ---------------------------------------------------------------- GAT gather+softmax+PV
__global__ __launch_bounds__(256) void k_gat(const float* __restrict__ h,
    const float* __restrict__ asrc, const float* __restrict__ adst,
    const int* __restrict__ nbr, const float* __restrict__ bias,
    float* __restrict__ f, float* __restrict__ x2out)
{
    int wid = threadIdx.x>>6, lane = threadIdx.x&63;
    int node = blockIdx.x*4 + wid;
    int hh = lane>>4;
    float ad = adst[(size_t)node*HHH+hh];
    int js[KK]; float e[KK];
    #pragma unroll
    for (int k=0;k<KK;k++){
        int j = nbr[node*KK+k] & (NNODE-1);    // clamp: garbage -> numeric error, never a fault
        js[k]=j;
        float ev = asrc[(size_t)j*HHH+hh] + ad;
        e[k] = ev>0.f ? ev : 0.2f*ev;          // leaky_relu 0.2
    }
    float m = e[0];
    #pragma unroll
    for (int k=1;k<KK;k++) m = fmaxf(m,e[k]);
    float s=0.f;
    #pragma unroll
    for (int k=0;k<KK;k++){ e[k]=__expf(e[k]-m); s+=e[k]; }
    float inv = 1.f/s;
    float acc=0.f;
    #pragma unroll
    for (int k=0;k<KK;k++)
        acc = fmaf(e[k]*inv, h[(size_t)js[k]*CC + lane], acc);
    float val = acc + bias[lane];
    val = val>0.f ? val : expm1f(val);          // elu
    f[(size_t)node*CC+lane]=val;
    float sq = val*val;
    #pragma unroll
    for (int s2=32;s2>0;s2>>=1) sq += __shfl_xor(sq, s2);
    if (lane==0) x2out[node]=sq;
}

// ---------------------------------------------------------------- final MLP + transpose-out
__global__ __launch_bounds__(256) void k_final(const float* __restrict__ f1,
    const float* __restrict__ f2, const float* __restrict__ Wm,
    const float* __restrict__ bm, float* __restrict__ out)
{
    __shared__ float Wl[2*CC*CC];   // 128x64 fp32 = 32 KB
    const int tid=threadIdx.x;
    for (int i=tid;i<2*CC*CC;i+=256) Wl[i]=Wm[i];
    __syncthreads();
    int node = blockIdx.x*256 + tid;
    int b = node>>12, n = node&(NPTS-1);
    float xr[2*CC];
    const float4* p1=(const float4*)(f1 + (size_t)node*CC);
    const float4* p2=(const float4*)(f2 + (size_t)node*CC);
    #pragma unroll
    for (int i=0;i<CC/4;i++){ float4 v=p1[i]; xr[4*i]=v.x; xr[4*i+1]=v.y; xr[4*i+2]=v.z; xr[4*i+3]=v.w; }
    #pragma unroll
    for (int i=0;i<CC/4;i++){ float4 v=p2[i]; xr[CC+4*i]=v.x; xr[CC+4*i+1]=v.y; xr[CC+4*i+2]=v.z; xr[CC+4*i+3]=v.w; }
    #pragma unroll 1
    for (int c4=0;c4<CC/4;c4++){
        float acc[4]={0,0,0,0};
        #pragma unroll
        for (int d=0;d<2*CC;d++){
            const float* wp = Wl + d*CC + c4*4;
            float xv=xr[d];
            acc[0]=fmaf(xv,wp[0],acc[0]); acc[1]=fmaf(xv,wp[1],acc[1]);
            acc[2]=fmaf(xv,wp[2],acc[2]); acc[3]=fmaf(xv,wp[3],acc[3]);
        }
        #pragma unroll
        for (int j=0;j<4;j++){
            int c=c4*4+j;
            float v = acc[j] + bm[c];
            v = v>0.f ? v : expm1f(v);
            out[(size_t)b*CC*NPTS + (size_t)c*NPTS + n] = v;
        }
    }
}

// ---------------------------------------------------------------- ws-too-small fallback
__global__ void k_zero(float* out, int n){
    int i = blockIdx.x*256 + threadIdx.x;
    if (i<n) out[i] = 0.f;
}

// ---------------------------------------------------------------- launcher
extern "C" void kernel_launch(void* const* d_in, const int* in_sizes, int n_in,
                              void* d_out, int out_size, void* d_ws, size_t ws_size,
                              hipStream_t stream) {
    const float* pf  = (const float*)d_in[0];
    const float* pt  = (const float*)d_in[1];
    const float* W1  = (const float*)d_in[2];
    const float* a1s = (const float*)d_in[3];
    const float* a1d = (const float*)d_in[4];
    const float* b1  = (const float*)d_in[5];
    const float* W2  = (const float*)d_in[6];
    const float* a2s = (const float*)d_in[7];
    const float* a2d = (const float*)d_in[8];
    const float* b2  = (const float*)d_in[9];
    const float* Wm  = (const float*)d_in[10];
    const float* bm  = (const float*)d_in[11];
    float* out = (float*)d_out;

    // ---- workspace layout (floats), ~14.5 MB; aliases:
    //   f2 <- xcat region (xcat dead after gemm1)
    //   knn partials live in dead regions: knn1 partd=h, parti=f1 (both written later);
    //   knn2 partd=h (dead again), parti=xcat (dead after gemm1; f2 written at gat2, after merge2)
    float* ws = (float*)d_ws;
    float* xcat  = ws;                             // 16384*68
    float* f2    = xcat;                           // alias
    float* h     = xcat + (size_t)NNODE*SD1;       // 16384*64  (>= 16384*32 partd)
    float* f1    = h    + (size_t)NNODE*CC;        // 16384*64  (>= 16384*32 parti)
    int*   nbr   = (int*)(f1 + (size_t)NNODE*CC);  // 16384*16
    float* x2    = (float*)(nbr + (size_t)NNODE*KK); // 16384
    float* asrc  = x2   + NNODE;                   // 16384*4
    float* adst  = asrc + (size_t)NNODE*HHH;       // 16384*4
    size_t need  = (size_t)((adst + (size_t)NNODE*HHH) - ws) * sizeof(float);
    if (ws_size < need) {   // diagnostic fallback: clean numeric fail, not a crash
        k_zero<<<(out_size+255)/256, 256, 0, stream>>>(out, out_size);
        return;
    }

    dim3 knnGrid(NPTS/64, BB, NSEG);   // 512 blocks x 512 thr -> 2 blocks/CU (4 waves/SIMD)

    k_prep<<<NNODE/256, 256, 0, stream>>>(pf, pt, xcat, x2);
    k_knn_seg<SD1><<<knnGrid, 512, 0, stream>>>(xcat, x2, h, (int*)f1);
    k_merge2<<<NNODE/256, 256, 0, stream>>>(h, (int*)f1, nbr);
    k_gemm_h<SD1, D1><<<NNODE/256, 256, 0, stream>>>(xcat, W1, a1s, a1d, h, asrc, adst);
    k_gat<<<NNODE/4, 256, 0, stream>>>(h, asrc, adst, nbr, b1, f1, x2);
    k_knn_seg<SD2><<<knnGrid, 512, 0, stream>>>(f1, x2, h, (int*)xcat);
    k_merge2<<<NNODE/256, 256, 0, stream>>>(h, (int*)xcat, nbr);
    k_gemm_h<SD2, CC><<<NNODE/256, 256, 0, stream>>>(f1, W2, a2s, a2d, h, asrc, adst);
    k_gat<<<NNODE/4, 256, 0, stream>>>(h, asrc, adst, nbr, b2, f2, x2);
    k_final<<<NNODE/256, 256, 0, stream>>>(f1, f2, Wm, bm, out);
}

// Round 8
// 976.691 us; speedup vs baseline: 5.5606x; 1.2865x over previous
//
#include <hip/hip_runtime.h>
#include <math.h>

#define BB   4
#define NPTS 4096
#define NNODE (BB*NPTS)
#define CC   64
#define HHH  4
#define KK   16
#define D1   67
#define SD1  68     // padded row stride for xcat
#define SD2  64
#define NSTR 4      // candidate streams (= waves) per knn block
#define NSEG 4      // candidate segments (blockIdx.z)
#define SEGC (NPTS/NSEG)     // 1024 candidates per segment
#define MSTD (NSTR*KK + 1)   // per-node merge stride in doubles (65)

// ---------------------------------------------------------------- prep:
// build xcat fp32 [NNODE][68] = [features(64) | coords(3) | 0pad] and ||x||^2
__global__ __launch_bounds__(256) void k_prep(const float* __restrict__ pf,
                                              const float* __restrict__ pt,
                                              float* __restrict__ xcat,
                                              float* __restrict__ x2)
{
    int node = blockIdx.x*256 + threadIdx.x;
    int b = node >> 12, n = node & (NPTS-1);
    const float* pfb = pf + (size_t)b*CC*NPTS + n;
    const float* ptb = pt + (size_t)b*3*NPTS + n;
    float* row = xcat + (size_t)node*SD1;
    float acc = 0.f;
    #pragma unroll 8
    for (int c=0;c<CC;c++){ float v = pfb[(size_t)c*NPTS]; row[c]=v; acc = fmaf(v,v,acc); }
    #pragma unroll
    for (int c=0;c<3;c++){ float v = ptb[(size_t)c*NPTS]; row[CC+c]=v; acc = fmaf(v,v,acc); }
    row[SD1-1]=0.f;
    x2[node]=acc;
}

// ---------------------------------------------------------------- f64 key pack
// us = monotone uint of fp32 distance (strictly monotone, bijective);
// key = us*4096 + local_idx  (exact integer in f64; < 2^44).
// Plain f64 '<' on keys == lexicographic (d, idx), lowest index first
// == jax.lax.top_k tie-break.
__device__ __forceinline__ double packdi(float dd, int lidx){
    unsigned u = __float_as_uint(dd);
    unsigned us = u ^ ((unsigned)((int)u >> 31) | 0x80000000u);
    return fma((double)us, 4096.0, (double)lidx);
}

// branchless sorted-16 insert: 16-level min/max sift (no divergence)
__device__ __forceinline__ void sift16(double (&dk)[KK], double v){
    #pragma unroll
    for (int j=0;j<KK;j++){
        double lo = fmin(dk[j], v);
        v = fmax(dk[j], v);
        dk[j] = lo;
    }
}

// ---------------------------------------------------------------- fused knn (per segment)
// block = 256 threads = 4 waves, owns 64 consecutive nodes (node = base + lane),
// scans candidate segment [seg*1024, (seg+1)*1024). wave w scans candidates
// c ≡ w (mod 4) ascending -> sorted register top-16 f64 keys per lane;
// block-internal 4-way merge -> sorted per-node 16-key list for this segment.
template<int SD>
__global__ __launch_bounds__(256) void k_knn_seg(const float* __restrict__ X,
    const float* __restrict__ x2, double* __restrict__ partd)
{
    // LDS: f64 merge array dominates; scan tile + t2 alias its head
    // (tile/t2 dead before md is written; phases separated by __syncthreads).
    __shared__ __align__(16) double md[64*MSTD];   // 33280 B [node][stream*16+entry]
    float* tile = (float*)md;              // 64*SD floats (<= 17408 B)
    float* t2   = (float*)md + 64*SD;      // 64 floats

    const int tid = threadIdx.x;
    const int w = tid>>6, l = tid&63;   // stream = wave id, node-lane = l
    const int b = blockIdx.y, seg = blockIdx.z;
    const int nodeBase = b*NPTS + blockIdx.x*64;
    const int node = nodeBase + l;
    const int nlocal = blockIdx.x*64 + l;   // node index within batch

    float4 xt[SD/4];
    const float4* xr = (const float4*)(X + (size_t)node*SD);
    #pragma unroll
    for (int i=0;i<SD/4;i++) xt[i]=xr[i];
    const float x2t = x2[node];

    double dk[KK];
    #pragma unroll
    for (int i=0;i<KK;i++) dk[i]=__builtin_inf();

    for (int t=0; t<SEGC/64; t++){
        int lcb = seg*SEGC + t*64;          // local candidate base (within batch)
        int cb  = b*NPTS + lcb;             // global
        __syncthreads();   // previous tile fully consumed
        { // stage 64 candidate rows (contiguous: row stride == SD)
            const float4* src = (const float4*)(X + (size_t)cb*SD);
            float4* dst = (float4*)tile;
            for (int i=tid; i<16*SD; i+=256) dst[i]=src[i];
            if (tid < 64) t2[tid]=x2[cb+tid];
        }
        __syncthreads();
        // wave w handles local candidates {w, w+4, ..., w+60}, ascending,
        // two per iteration (c0, c0+4) for 4 independent FMA chains.
        #pragma unroll 1
        for (int q=0;q<8;q++){
            int c0 = w + 8*q, c1 = c0 + 4;
            float a0=0.f,b0=0.f,a1=0.f,b1=0.f;
            const float* r0 = tile + c0*SD;
            const float* r1 = tile + c1*SD;
            #pragma unroll
            for (int i=0;i<SD/4;i++){
                float4 v = xt[i];
                const float* p0 = r0 + 4*i;
                const float* p1 = r1 + 4*i;
                if ((i&1)==0){
                    a0 = fmaf(v.w,p0[3], fmaf(v.z,p0[2], fmaf(v.y,p0[1], fmaf(v.x,p0[0], a0))));
                    a1 = fmaf(v.w,p1[3], fmaf(v.z,p1[2], fmaf(v.y,p1[1], fmaf(v.x,p1[0], a1))));
                } else {
                    b0 = fmaf(v.w,p0[3], fmaf(v.z,p0[2], fmaf(v.y,p0[1], fmaf(v.x,p0[0], b0))));
                    b1 = fmaf(v.w,p1[3], fmaf(v.z,p1[2], fmaf(v.y,p1[1], fmaf(v.x,p1[0], b1))));
                }
            }
            float dot0=a0+b0, dot1=a1+b1;
            // reference order: (x2_t - 2*dot) + x2_c   (2*dot exact, fmaf == np rounding)
            float dd0 = fmaf(-2.f, dot0, x2t) + t2[c0];
            float dd1 = fmaf(-2.f, dot1, x2t) + t2[c1];
            int lc0 = lcb + c0, lc1 = lcb + c1;
            double pd0 = packdi(dd0, lc0);
            double pd1 = packdi(dd1, lc1);
            if (lc0==nlocal) pd0 = __builtin_inf();   // exclude self
            if (lc1==nlocal) pd1 = __builtin_inf();
            sift16(dk, pd0);
            sift16(dk, pd1);
        }
    }
    // ---- publish sorted per-stream key lists (tile/t2 dead from here)
    __syncthreads();
    #pragma unroll
    for (int i=0;i<KK;i++) md[l*MSTD + w*KK + i]=dk[i];
    __syncthreads();
    // ---- serial 4-way merge with register-cached heads: thread l (<64) owns node l;
    // writes this segment's sorted 16-key list to global partials.
    if (tid < 64){
        const double* mdl = md + tid*MSTD;
        double hd[NSTR]; int pp[NSTR];
        #pragma unroll
        for (int s=0;s<NSTR;s++){ pp[s]=0; hd[s]=mdl[s*KK]; }
        size_t obase = ((size_t)(nodeBase + tid)*NSEG + seg)*KK;
        #pragma unroll 1
        for (int r=0;r<KK;r++){
            double bd=hd[0]; int bw=0;
            #pragma unroll
            for (int s=1;s<NSTR;s++){
                if (hd[s]<bd){ bd=hd[s]; bw=s; }   // keys strictly distinct
            }
            partd[obase + r] = bd;
            #pragma unroll
            for (int s=0;s<NSTR;s++){
                if (bw==s){
                    int np = ++pp[s];
                    double nv = mdl[s*KK + np];  // np==KK reads pad/next; discarded
                    hd[s] = (np < KK) ? nv : __builtin_inf();
                }
            }
        }
    }
}

// ---------------------------------------------------------------- merge NSEG sorted key lists -> nbr
__global__ __launch_bounds__(256) void k_merge(const double* __restrict__ partd,
    int* __restrict__ nbr)
{
    int node = blockIdx.x*256 + threadIdx.x;
    int bbase = (node >> 12) << 12;   // b*NPTS
    const double* p = partd + (size_t)node*NSEG*KK;
    double hd[NSEG]; int pp[NSEG];
    #pragma unroll
    for (int s=0;s<NSEG;s++){ pp[s]=0; hd[s]=p[s*KK]; }
    int obase = node*KK;
    #pragma unroll 1
    for (int r=0;r<KK;r++){
        double bd=hd[0]; int bw=0;
        #pragma unroll
        for (int s=1;s<NSEG;s++){
            if (hd[s]<bd){ bd=hd[s]; bw=s; }
        }
        // exact unpack: bd = us*4096 + lidx, integers < 2^53
        double qq = floor(bd * (1.0/4096.0));
        int lidx = (int)(bd - qq*4096.0);
        nbr[obase + r] = bbase + lidx;
        #pragma unroll
        for (int s=0;s<NSEG;s++){
            if (bw==s){
                int np = ++pp[s];
                double nv = p[s*KK + np];   // np==KK overreads 8B into live ws; discarded
                hd[s] = (np < KK) ? nv : __builtin_inf();
            }
        }
    }
}

// ---------------------------------------------------------------- h = X@W, asrc, adst
template<int SD, int D>
__global__ __launch_bounds__(256) void k_gemm_h(const float* __restrict__ X,
    const float* __restrict__ W, const float* __restrict__ a_s,
    const float* __restrict__ a_d,
    float* __restrict__ h, float* __restrict__ asrc, float* __restrict__ adst)
{
    __shared__ float Wl[D*CC];
    __shared__ float asl[CC], adl[CC];
    const int tid = threadIdx.x;
    for (int i=tid;i<D*CC;i+=256) Wl[i]=W[i];
    if (tid<CC){ asl[tid]=a_s[tid]; adl[tid]=a_d[tid]; }
    __syncthreads();

    const int node = blockIdx.x*256 + tid;
    float xr[SD];
    const float4* xp = (const float4*)(X + (size_t)node*SD);
    #pragma unroll
    for (int i=0;i<SD/4;i++){ float4 v=xp[i]; xr[4*i]=v.x; xr[4*i+1]=v.y; xr[4*i+2]=v.z; xr[4*i+3]=v.w; }

    float sacc[HHH]={0,0,0,0}, dacc[HHH]={0,0,0,0};
    float* hrow = h + (size_t)node*CC;
    #pragma unroll 1
    for (int c4=0;c4<CC/4;c4++){
        float acc[4]={0,0,0,0};
        #pragma unroll
        for (int d=0;d<D;d++){
            const float* wp = Wl + d*CC + c4*4;
            float xv = xr[d];
            acc[0]=fmaf(xv,wp[0],acc[0]); acc[1]=fmaf(xv,wp[1],acc[1]);
            acc[2]=fmaf(xv,wp[2],acc[2]); acc[3]=fmaf(xv,wp[3],acc[3]);
        }
        int hh = c4 >> 2;
        #pragma unroll
        for (int j=0;j<4;j++){
            int c = c4*4+j;
            sacc[hh] = fmaf(acc[j], asl[c], sacc[hh]);
            dacc[hh] = fmaf(acc[j], adl[c], dacc[hh]);
        }
        ((float4*)hrow)[c4] = make_float4(acc[0],acc[1],acc[2],acc[3]);
    }
    #pragma unroll
    for (int q=0;q<HHH;q++){ asrc[(size_t)node*HHH+q]=sacc[q]; adst[(size_t)node*HHH+q]=dacc[q]; }
}

// ---------------------------------------------------------------- GAT gather+softmax+PV
__global__ __launch_bounds__(256) void k_gat(const float* __restrict__ h,
    const float* __restrict__ asrc, const float* __restrict__ adst,
    const int* __restrict__ nbr, const float* __restrict__ bias,
    float* __restrict__ f, float* __restrict__ x2out)
{
    int wid = threadIdx.x>>6, lane = threadIdx.x&63;
    int node = blockIdx.x*4 + wid;
    int hh = lane>>4;
    float ad = adst[(size_t)node*HHH+hh];
    int js[KK]; float e[KK];
    #pragma unroll
    for (int k=0;k<KK;k++){
        int j = nbr[node*KK+k] & (NNODE-1);    // clamp: garbage -> numeric error, never a fault
        js[k]=j;
        float ev = asrc[(size_t)j*HHH+hh] + ad;
        e[k] = ev>0.f ? ev : 0.2f*ev;          // leaky_relu 0.2
    }
    float m = e[0];
    #pragma unroll
    for (int k=1;k<KK;k++) m = fmaxf(m,e[k]);
    float s=0.f;
    #pragma unroll
    for (int k=0;k<KK;k++){ e[k]=__expf(e[k]-m); s+=e[k]; }
    float inv = 1.f/s;
    float acc=0.f;
    #pragma unroll
    for (int k=0;k<KK;k++)
        acc = fmaf(e[k]*inv, h[(size_t)js[k]*CC + lane], acc);
    float val = acc + bias[lane];
    val = val>0.f ? val : expm1f(val);          // elu
    f[(size_t)node*CC+lane]=val;
    float sq = val*val;
    #pragma unroll
    for (int s2=32;s2>0;s2>>=1) sq += __shfl_xor(sq, s2);
    if (lane==0) x2out[node]=sq;
}

// ---------------------------------------------------------------- final MLP + transpose-out
__global__ __launch_bounds__(256) void k_final(const float* __restrict__ f1,
    const float* __restrict__ f2, const float* __restrict__ Wm,
    const float* __restrict__ bm, float* __restrict__ out)
{
    __shared__ float Wl[2*CC*CC];   // 128x64 fp32 = 32 KB
    const int tid=threadIdx.x;
    for (int i=tid;i<2*CC*CC;i+=256) Wl[i]=Wm[i];
    __syncthreads();
    int node = blockIdx.x*256 + tid;
    int b = node>>12, n = node&(NPTS-1);
    float xr[2*CC];
    const float4* p1=(const float4*)(f1 + (size_t)node*CC);
    const float4* p2=(const float4*)(f2 + (size_t)node*CC);
    #pragma unroll
    for (int i=0;i<CC/4;i++){ float4 v=p1[i]; xr[4*i]=v.x; xr[4*i+1]=v.y; xr[4*i+2]=v.z; xr[4*i+3]=v.w; }
    #pragma unroll
    for (int i=0;i<CC/4;i++){ float4 v=p2[i]; xr[CC+4*i]=v.x; xr[CC+4*i+1]=v.y; xr[CC+4*i+2]=v.z; xr[CC+4*i+3]=v.w; }
    #pragma unroll 1
    for (int c4=0;c4<CC/4;c4++){
        float acc[4]={0,0,0,0};
        #pragma unroll
        for (int d=0;d<2*CC;d++){
            const float* wp = Wl + d*CC + c4*4;
            float xv=xr[d];
            acc[0]=fmaf(xv,wp[0],acc[0]); acc[1]=fmaf(xv,wp[1],acc[1]);
            acc[2]=fmaf(xv,wp[2],acc[2]); acc[3]=fmaf(xv,wp[3],acc[3]);
        }
        #pragma unroll
        for (int j=0;j<4;j++){
            int c=c4*4+j;
            float v = acc[j] + bm[c];
            v = v>0.f ? v : expm1f(v);
            out[(size_t)b*CC*NPTS + (size_t)c*NPTS + n] = v;
        }
    }
}

// ---------------------------------------------------------------- ws-too-small fallback
__global__ void k_zero(float* out, int n){
    int i = blockIdx.x*256 + threadIdx.x;
    if (i<n) out[i] = 0.f;
}

// ---------------------------------------------------------------- launcher
extern "C" void kernel_launch(void* const* d_in, const int* in_sizes, int n_in,
                              void* d_out, int out_size, void* d_ws, size_t ws_size,
                              hipStream_t stream) {
    const float* pf  = (const float*)d_in[0];
    const float* pt  = (const float*)d_in[1];
    const float* W1  = (const float*)d_in[2];
    const float* a1s = (const float*)d_in[3];
    const float* a1d = (const float*)d_in[4];
    const float* b1  = (const float*)d_in[5];
    const float* W2  = (const float*)d_in[6];
    const float* a2s = (const float*)d_in[7];
    const float* a2d = (const float*)d_in[8];
    const float* b2  = (const float*)d_in[9];
    const float* Wm  = (const float*)d_in[10];
    const float* bm  = (const float*)d_in[11];
    float* out = (float*)d_out;

    // ---- workspace layout (floats), ~14.5 MB; aliases:
    //   f2 <- xcat region (xcat dead after gemm1)
    //   f64 knn partials (8 MB) live in dead regions:
    //     knn1: h+f1 region (exactly 8 MB; both written after merge1)
    //     knn2: xcat+h region (8.65 MB; xcat dead after gemm1, f2 written at gat2, h rewritten at gemm2)
    float* ws = (float*)d_ws;
    float* xcat  = ws;                             // 16384*68
    float* f2    = xcat;                           // alias
    float* h     = xcat + (size_t)NNODE*SD1;       // 16384*64
    float* f1    = h    + (size_t)NNODE*CC;        // 16384*64
    int*   nbr   = (int*)(f1 + (size_t)NNODE*CC);  // 16384*16
    float* x2    = (float*)(nbr + (size_t)NNODE*KK); // 16384
    float* asrc  = x2   + NNODE;                   // 16384*4
    float* adst  = asrc + (size_t)NNODE*HHH;       // 16384*4
    double* part1 = (double*)h;                    // 8 MB over h+f1
    double* part2 = (double*)xcat;                 // 8 MB over xcat+h
    size_t need  = (size_t)((adst + (size_t)NNODE*HHH) - ws) * sizeof(float);
    if (ws_size < need) {   // diagnostic fallback: clean numeric fail, not a crash
        k_zero<<<(out_size+255)/256, 256, 0, stream>>>(out, out_size);
        return;
    }

    dim3 knnGrid(NPTS/64, BB, NSEG);   // 1024 blocks x 256 thr (4 waves, 33.3 KB LDS)

    k_prep<<<NNODE/256, 256, 0, stream>>>(pf, pt, xcat, x2);
    k_knn_seg<SD1><<<knnGrid, 256, 0, stream>>>(xcat, x2, part1);
    k_merge<<<NNODE/256, 256, 0, stream>>>(part1, nbr);
    k_gemm_h<SD1, D1><<<NNODE/256, 256, 0, stream>>>(xcat, W1, a1s, a1d, h, asrc, adst);
    k_gat<<<NNODE/4, 256, 0, stream>>>(h, asrc, adst, nbr, b1, f1, x2);
    k_knn_seg<SD2><<<knnGrid, 256, 0, stream>>>(f1, x2, part2);
    k_merge<<<NNODE/256, 256, 0, stream>>>(part2, nbr);
    k_gemm_h<SD2, CC><<<NNODE/256, 256, 0, stream>>>(f1, W2, a2s, a2d, h, asrc, adst);
    k_gat<<<NNODE/4, 256, 0, stream>>>(h, asrc, adst, nbr, b2, f2, x2);
    k_final<<<NNODE/256, 256, 0, stream>>>(f1, f2, Wm, bm, out);
}

// Round 9
// 820.441 us; speedup vs baseline: 6.6195x; 1.1904x over previous
//
#include <hip/hip_runtime.h>
#include <math.h>

#define BB   4
#define NPTS 4096
#define NNODE (BB*NPTS)
#define CC   64
#define HHH  4
#define KK   16
#define D1   67
#define SD1  68     // padded row stride for xcat
#define SD2  64
#define NSTR 4      // candidate streams (= waves) per knn block
#define NSEG 4      // candidate segments (blockIdx.z)
#define SEGC (NPTS/NSEG)     // 1024 candidates per segment
#define MSTD (NSTR*KK + 1)   // per-node merge stride in doubles (65)

// ---------------------------------------------------------------- prep:
// build xcat fp32 [NNODE][68] = [features(64) | coords(3) | 0pad] and ||x||^2
__global__ __launch_bounds__(256) void k_prep(const float* __restrict__ pf,
                                              const float* __restrict__ pt,
                                              float* __restrict__ xcat,
                                              float* __restrict__ x2)
{
    int node = blockIdx.x*256 + threadIdx.x;
    int b = node >> 12, n = node & (NPTS-1);
    const float* pfb = pf + (size_t)b*CC*NPTS + n;
    const float* ptb = pt + (size_t)b*3*NPTS + n;
    float* row = xcat + (size_t)node*SD1;
    float acc = 0.f;
    #pragma unroll 8
    for (int c=0;c<CC;c++){ float v = pfb[(size_t)c*NPTS]; row[c]=v; acc = fmaf(v,v,acc); }
    #pragma unroll
    for (int c=0;c<3;c++){ float v = ptb[(size_t)c*NPTS]; row[CC+c]=v; acc = fmaf(v,v,acc); }
    row[SD1-1]=0.f;
    x2[node]=acc;
}

// ---------------------------------------------------------------- f64 key pack
// us = monotone uint of fp32 distance (strictly monotone, bijective);
// key = us*4096 + local_idx  (exact integer in f64; < 2^44).
// Plain f64 '<' on keys == lexicographic (d, idx), lowest index first
// == jax.lax.top_k tie-break.
__device__ __forceinline__ double packdi(float dd, int lidx){
    unsigned u = __float_as_uint(dd);
    unsigned us = u ^ ((unsigned)((int)u >> 31) | 0x80000000u);
    return fma((double)us, 4096.0, (double)lidx);
}

// branchless sorted-16 insert: 16-level min/max sift (no divergence)
__device__ __forceinline__ void sift16(double (&dk)[KK], double v){
    #pragma unroll
    for (int j=0;j<KK;j++){
        double lo = fmin(dk[j], v);
        v = fmax(dk[j], v);
        dk[j] = lo;
    }
}

// ---------------------------------------------------------------- fused knn (per segment)
// block = 256 threads = 4 waves, owns 64 consecutive nodes (node = base + lane),
// scans candidate segment [seg*1024, (seg+1)*1024). wave w scans candidates
// c ≡ w (mod 4) ascending. Candidate rows are WAVE-UNIFORM -> read through the
// scalar pipe (s_load into SGPRs, forced via readfirstlane-uniform address);
// the dot is v_fmac(sgpr, vgpr). No LDS staging, no DS broadcast reads.
// Per-lane sorted register top-16 f64 keys; block-internal 4-way merge ->
// sorted per-node 16-key list for this segment.
template<int SD>
__global__ __launch_bounds__(256) void k_knn_seg(const float* __restrict__ X,
    const float* __restrict__ x2, double* __restrict__ partd)
{
    __shared__ __align__(16) double md[64*MSTD];   // 33280 B [node][stream*16+entry]

    const int tid = threadIdx.x;
    const int w = __builtin_amdgcn_readfirstlane(tid>>6);  // wave id, provably uniform
    const int l = tid&63;
    const int b = blockIdx.y, seg = blockIdx.z;
    const int nodeBase = b*NPTS + blockIdx.x*64;
    const int node = nodeBase + l;
    const int nlocal = blockIdx.x*64 + l;   // node index within batch

    float4 xt[SD/4];
    const float4* xr = (const float4*)(X + (size_t)node*SD);
    #pragma unroll
    for (int i=0;i<SD/4;i++) xt[i]=xr[i];
    const float x2t = x2[node];

    double dk[KK];
    #pragma unroll
    for (int i=0;i<KK;i++) dk[i]=__builtin_inf();

    const float* Xb  = X  + (size_t)b*NPTS*SD;   // batch base (uniform)
    const float* x2b = x2 + (size_t)b*NPTS;

    #pragma unroll 1
    for (int q=0;q<SEGC/NSTR;q++){
        int lc = seg*SEGC + q*NSTR + w;          // local candidate idx (uniform)
        const float4* crow = (const float4*)(Xb + (size_t)lc*SD);  // uniform -> s_load
        float x2c = x2b[lc];                     // uniform -> s_load
        float a0=0.f,a1=0.f,a2=0.f,a3=0.f;       // 4 chains -> ILP 4
        #pragma unroll
        for (int i=0;i<SD/4;i++){
            float4 cv = crow[i];                 // SGPRs
            float4 xv = xt[i];
            a0 = fmaf(cv.x, xv.x, a0);
            a1 = fmaf(cv.y, xv.y, a1);
            a2 = fmaf(cv.z, xv.z, a2);
            a3 = fmaf(cv.w, xv.w, a3);
        }
        float dot = (a0+a1)+(a2+a3);
        // reference order: (x2_t - 2*dot) + x2_c   (2*dot exact, fmaf == np rounding)
        float dd = fmaf(-2.f, dot, x2t) + x2c;
        double pd = packdi(dd, lc);
        if (lc==nlocal) pd = __builtin_inf();    // exclude self
        sift16(dk, pd);
    }
    // ---- publish sorted per-stream key lists
    #pragma unroll
    for (int i=0;i<KK;i++) md[l*MSTD + w*KK + i]=dk[i];
    __syncthreads();
    // ---- serial 4-way merge with register-cached heads: thread l (<64) owns node l;
    // writes this segment's sorted 16-key list to global partials.
    if (tid < 64){
        const double* mdl = md + tid*MSTD;
        double hd[NSTR]; int pp[NSTR];
        #pragma unroll
        for (int s=0;s<NSTR;s++){ pp[s]=0; hd[s]=mdl[s*KK]; }
        size_t obase = ((size_t)(nodeBase + tid)*NSEG + seg)*KK;
        #pragma unroll 1
        for (int r=0;r<KK;r++){
            double bd=hd[0]; int bw=0;
            #pragma unroll
            for (int s=1;s<NSTR;s++){
                if (hd[s]<bd){ bd=hd[s]; bw=s; }   // keys strictly distinct
            }
            partd[obase + r] = bd;
            #pragma unroll
            for (int s=0;s<NSTR;s++){
                if (bw==s){
                    int np = ++pp[s];
                    double nv = mdl[s*KK + np];  // np==KK reads pad/next; discarded
                    hd[s] = (np < KK) ? nv : __builtin_inf();
                }
            }
        }
    }
}

// ---------------------------------------------------------------- merge NSEG sorted key lists -> nbr
__global__ __launch_bounds__(256) void k_merge(const double* __restrict__ partd,
    int* __restrict__ nbr)
{
    int node = blockIdx.x*256 + threadIdx.x;
    int bbase = (node >> 12) << 12;   // b*NPTS
    const double* p = partd + (size_t)node*NSEG*KK;
    double hd[NSEG]; int pp[NSEG];
    #pragma unroll
    for (int s=0;s<NSEG;s++){ pp[s]=0; hd[s]=p[s*KK]; }
    int obase = node*KK;
    #pragma unroll 1
    for (int r=0;r<KK;r++){
        double bd=hd[0]; int bw=0;
        #pragma unroll
        for (int s=1;s<NSEG;s++){
            if (hd[s]<bd){ bd=hd[s]; bw=s; }
        }
        // exact unpack: bd = us*4096 + lidx, integers < 2^53
        double qq = floor(bd * (1.0/4096.0));
        int lidx = (int)(bd - qq*4096.0);
        nbr[obase + r] = bbase + lidx;
        #pragma unroll
        for (int s=0;s<NSEG;s++){
            if (bw==s){
                int np = ++pp[s];
                double nv = p[s*KK + np];   // np==KK overreads 8B into live ws; discarded
                hd[s] = (np < KK) ? nv : __builtin_inf();
            }
        }
    }
}

// ---------------------------------------------------------------- h = X@W, asrc, adst
template<int SD, int D>
__global__ __launch_bounds__(256) void k_gemm_h(const float* __restrict__ X,
    const float* __restrict__ W, const float* __restrict__ a_s,
    const float* __restrict__ a_d,
    float* __restrict__ h, float* __restrict__ asrc, float* __restrict__ adst)
{
    __shared__ float Wl[D*CC];
    __shared__ float asl[CC], adl[CC];
    const int tid = threadIdx.x;
    for (int i=tid;i<D*CC;i+=256) Wl[i]=W[i];
    if (tid<CC){ asl[tid]=a_s[tid]; adl[tid]=a_d[tid]; }
    __syncthreads();

    const int node = blockIdx.x*256 + tid;
    float xr[SD];
    const float4* xp = (const float4*)(X + (size_t)node*SD);
    #pragma unroll
    for (int i=0;i<SD/4;i++){ float4 v=xp[i]; xr[4*i]=v.x; xr[4*i+1]=v.y; xr[4*i+2]=v.z; xr[4*i+3]=v.w; }

    float sacc[HHH]={0,0,0,0}, dacc[HHH]={0,0,0,0};
    float* hrow = h + (size_t)node*CC;
    #pragma unroll 1
    for (int c4=0;c4<CC/4;c4++){
        float acc[4]={0,0,0,0};
        #pragma unroll
        for (int d=0;d<D;d++){
            const float* wp = Wl + d*CC + c4*4;
            float xv = xr[d];
            acc[0]=fmaf(xv,wp[0],acc[0]); acc[1]=fmaf(xv,wp[1],acc[1]);
            acc[2]=fmaf(xv,wp[2],acc[2]); acc[3]=fmaf(xv,wp[3],acc[3]);
        }
        int hh = c4 >> 2;
        #pragma unroll
        for (int j=0;j<4;j++){
            int c = c4*4+j;
            sacc[hh] = fmaf(acc[j], asl[c], sacc[hh]);
            dacc[hh] = fmaf(acc[j], adl[c], dacc[hh]);
        }
        ((float4*)hrow)[c4] = make_float4(acc[0],acc[1],acc[2],acc[3]);
    }
    #pragma unroll
    for (int q=0;q<HHH;q++){ asrc[(size_t)node*HHH+q]=sacc[q]; adst[(size_t)node*HHH+q]=dacc[q]; }
}

// ---------------------------------------------------------------- GAT gather+softmax+PV
__global__ __launch_bounds__(256) void k_gat(const float* __restrict__ h,
    const float* __restrict__ asrc, const float* __restrict__ adst,
    const int* __restrict__ nbr, const float* __restrict__ bias,
    float* __restrict__ f, float* __restrict__ x2out)
{
    int wid = threadIdx.x>>6, lane = threadIdx.x&63;
    int node = blockIdx.x*4 + wid;
    int hh = lane>>4;
    float ad = adst[(size_t)node*HHH+hh];
    int js[KK]; float e[KK];
    #pragma unroll
    for (int k=0;k<KK;k++){
        int j = nbr[node*KK+k] & (NNODE-1);    // clamp: garbage -> numeric error, never a fault
        js[k]=j;
        float ev = asrc[(size_t)j*HHH+hh] + ad;
        e[k] = ev>0.f ? ev : 0.2f*ev;          // leaky_relu 0.2
    }
    float m = e[0];
    #pragma unroll
    for (int k=1;k<KK;k++) m = fmaxf(m,e[k]);
    float s=0.f;
    #pragma unroll
    for (int k=0;k<KK;k++){ e[k]=__expf(e[k]-m); s+=e[k]; }
    float inv = 1.f/s;
    float acc=0.f;
    #pragma unroll
    for (int k=0;k<KK;k++)
        acc = fmaf(e[k]*inv, h[(size_t)js[k]*CC + lane], acc);
    float val = acc + bias[lane];
    val = val>0.f ? val : expm1f(val);          // elu
    f[(size_t)node*CC+lane]=val;
    float sq = val*val;
    #pragma unroll
    for (int s2=32;s2>0;s2>>=1) sq += __shfl_xor(sq, s2);
    if (lane==0) x2out[node]=sq;
}

// ---------------------------------------------------------------- final MLP + transpose-out
__global__ __launch_bounds__(256) void k_final(const float* __restrict__ f1,
    const float* __restrict__ f2, const float* __restrict__ Wm,
    const float* __restrict__ bm, float* __restrict__ out)
{
    __shared__ float Wl[2*CC*CC];   // 128x64 fp32 = 32 KB
    const int tid=threadIdx.x;
    for (int i=tid;i<2*CC*CC;i+=256) Wl[i]=Wm[i];
    __syncthreads();
    int node = blockIdx.x*256 + tid;
    int b = node>>12, n = node&(NPTS-1);
    float xr[2*CC];
    const float4* p1=(const float4*)(f1 + (size_t)node*CC);
    const float4* p2=(const float4*)(f2 + (size_t)node*CC);
    #pragma unroll
    for (int i=0;i<CC/4;i++){ float4 v=p1[i]; xr[4*i]=v.x; xr[4*i+1]=v.y; xr[4*i+2]=v.z; xr[4*i+3]=v.w; }
    #pragma unroll
    for (int i=0;i<CC/4;i++){ float4 v=p2[i]; xr[CC+4*i]=v.x; xr[CC+4*i+1]=v.y; xr[CC+4*i+2]=v.z; xr[CC+4*i+3]=v.w; }
    #pragma unroll 1
    for (int c4=0;c4<CC/4;c4++){
        float acc[4]={0,0,0,0};
        #pragma unroll
        for (int d=0;d<2*CC;d++){
            const float* wp = Wl + d*CC + c4*4;
            float xv=xr[d];
            acc[0]=fmaf(xv,wp[0],acc[0]); acc[1]=fmaf(xv,wp[1],acc[1]);
            acc[2]=fmaf(xv,wp[2],acc[2]); acc[3]=fmaf(xv,wp[3],acc[3]);
        }
        #pragma unroll
        for (int j=0;j<4;j++){
            int c=c4*4+j;
            float v = acc[j] + bm[c];
            v = v>0.f ? v : expm1f(v);
            out[(size_t)b*CC*NPTS + (size_t)c*NPTS + n] = v;
        }
    }
}

// ---------------------------------------------------------------- ws-too-small fallback
__global__ void k_zero(float* out, int n){
    int i = blockIdx.x*256 + threadIdx.x;
    if (i<n) out[i] = 0.f;
}

// ---------------------------------------------------------------- launcher
extern "C" void kernel_launch(void* const* d_in, const int* in_sizes, int n_in,
                              void* d_out, int out_size, void* d_ws, size_t ws_size,
                              hipStream_t stream) {
    const float* pf  = (const float*)d_in[0];
    const float* pt  = (const float*)d_in[1];
    const float* W1  = (const float*)d_in[2];
    const float* a1s = (const float*)d_in[3];
    const float* a1d = (const float*)d_in[4];
    const float* b1  = (const float*)d_in[5];
    const float* W2  = (const float*)d_in[6];
    const float* a2s = (const float*)d_in[7];
    const float* a2d = (const float*)d_in[8];
    const float* b2  = (const float*)d_in[9];
    const float* Wm  = (const float*)d_in[10];
    const float* bm  = (const float*)d_in[11];
    float* out = (float*)d_out;

    // ---- workspace layout (floats), ~14.5 MB; aliases:
    //   f2 <- xcat region (xcat dead after gemm1)
    //   f64 knn partials (8 MB) live in dead regions:
    //     knn1: h+f1 region (exactly 8 MB; both written after merge1)
    //     knn2: xcat+h region (8.65 MB; xcat dead after gemm1, f2 written at gat2, h rewritten at gemm2)
    float* ws = (float*)d_ws;
    float* xcat  = ws;                             // 16384*68
    float* f2    = xcat;                           // alias
    float* h     = xcat + (size_t)NNODE*SD1;       // 16384*64
    float* f1    = h    + (size_t)NNODE*CC;        // 16384*64
    int*   nbr   = (int*)(f1 + (size_t)NNODE*CC);  // 16384*16
    float* x2    = (float*)(nbr + (size_t)NNODE*KK); // 16384
    float* asrc  = x2   + NNODE;                   // 16384*4
    float* adst  = asrc + (size_t)NNODE*HHH;       // 16384*4
    double* part1 = (double*)h;                    // 8 MB over h+f1
    double* part2 = (double*)xcat;                 // 8 MB over xcat+h
    size_t need  = (size_t)((adst + (size_t)NNODE*HHH) - ws) * sizeof(float);
    if (ws_size < need) {   // diagnostic fallback: clean numeric fail, not a crash
        k_zero<<<(out_size+255)/256, 256, 0, stream>>>(out, out_size);
        return;
    }

    dim3 knnGrid(NPTS/64, BB, NSEG);   // 1024 blocks x 256 thr = exactly 4 blocks/CU

    k_prep<<<NNODE/256, 256, 0, stream>>>(pf, pt, xcat, x2);
    k_knn_seg<SD1><<<knnGrid, 256, 0, stream>>>(xcat, x2, part1);
    k_merge<<<NNODE/256, 256, 0, stream>>>(part1, nbr);
    k_gemm_h<SD1, D1><<<NNODE/256, 256, 0, stream>>>(xcat, W1, a1s, a1d, h, asrc, adst);
    k_gat<<<NNODE/4, 256, 0, stream>>>(h, asrc, adst, nbr, b1, f1, x2);
    k_knn_seg<SD2><<<knnGrid, 256, 0, stream>>>(f1, x2, part2);
    k_merge<<<NNODE/256, 256, 0, stream>>>(part2, nbr);
    k_gemm_h<SD2, CC><<<NNODE/256, 256, 0, stream>>>(f1, W2, a2s, a2d, h, asrc, adst);
    k_gat<<<NNODE/4, 256, 0, stream>>>(h, asrc, adst, nbr, b2, f2, x2);
    k_final<<<NNODE/256, 256, 0, stream>>>(f1, f2, Wm, bm, out);
}